// Round 10
// baseline (6051.236 us; speedup 1.0000x reference)
//
#include <hip/hip_runtime.h>
#include <cmath>

#define TSTEPS 256
#define DIM 1024
#define GST 35            // gate scratch col-stride

typedef _Float16 half8v __attribute__((ext_vector_type(8)));
typedef float f32x4 __attribute__((ext_vector_type(4)));
typedef unsigned long long u64;

// ws layout:
//   h0s : [256 t][64][1024] fp16, write-once per launch (33.55 MB)
//   h1s : [256 t][64][1024] fp16, write-once (33.55 MB)
//   cnts: leaf0[(p*16+leaf)*16], leaf1[...] (131,072 uints, 512 KB)
// Phase p: cell0 computes h0[t=p] (reads x[p] fp32 direct, h0s[p-1]);
// cell1 computes h1[t=p-1] (reads h0s[p-1], h1s[p-2]).
// KEY: every h address is written exactly once (scoped store -> L3) and read
// only after its leaf flags -> plain CACHED consumer loads are coherent with
// NO fences/invalidates; per-XCD L2 amplifies the broadcast (48 MB/phase of
// fabric traffic in R9 -> ~3 MB/phase L3->L2 + L2-served rest).

__global__ void prologue(unsigned* __restrict__ cnts)
{
    unsigned gid = blockIdx.x * blockDim.x + threadIdx.x;
    if (gid < 131072u) cnts[gid] = 0u;
}

// 256 blocks x 512 threads (8 waves). Blocks 0..127: cell0; 128..255: cell1.
// Block owns 32 gate-cols = 8 h-dims. Wave kq owns K-slice [kq*256,+256),
// weights in registers (16 x half8v). A[4][8] burst-loaded. Signal: 16 leaf
// counters/cell/phase (8 adds each, 64B apart); wait: wave0 lanes poll leaves
// in parallel + ballot, s_sleep pacing.
__global__ __launch_bounds__(512, 2)
void lstm_persistent(const float* __restrict__ x,
                     const float* __restrict__ Wx0, const float* __restrict__ Wh0,
                     const float* __restrict__ b0,
                     const float* __restrict__ Wx1, const float* __restrict__ Wh1,
                     const float* __restrict__ b1,
                     _Float16* __restrict__ h0s, _Float16* __restrict__ h1s,
                     unsigned* __restrict__ cnts, float* __restrict__ out)
{
    extern __shared__ char smem[];
    _Float16* wfrag = (_Float16*)smem;          // 128 KB staging (dead after init)
    float*    gates = (float*)smem;             // [8 kq][64 m][GST] fp32, aliases

    const int tid  = threadIdx.x;
    const int blk  = blockIdx.x;
    const int cell = blk >> 7;
    const int wb   = blk & 127;
    const int lane = tid & 63, kq = tid >> 6;
    const int n15 = lane & 15, q = lane >> 4;

    unsigned* leaf0 = cnts;                     // [(p*16+leaf)*16]
    unsigned* leaf1 = cnts + 65536;
    unsigned* leafm = cell ? leaf1 : leaf0;

    // ---- one-time: weights -> LDS in B-fragment order (fp32->fp16) ----
    const float* m0 = cell ? Wx1 : Wx0;   // K rows 0..1023  (x or h0)
    const float* m1 = cell ? Wh1 : Wh0;   // K rows 1024..2047 (h0 or h1)
    for (int idx = tid; idx < 16384; idx += 512) {
        int k = idx >> 3;
        int cc0 = (idx & 7) * 4;
        int g = cc0 >> 3, c = cc0 & 7;
        const float* src = (k < 1024 ? m0 + (size_t)k * 4096
                                     : m1 + (size_t)(k - 1024) * 4096)
                           + g * 1024 + wb * 8 + c;
        float4 v = *(const float4*)src;
        int skq = k >> 8, kt = (k >> 5) & 7, sq = (k >> 3) & 3, j = k & 7;
        float vv[4] = {v.x, v.y, v.z, v.w};
        #pragma unroll
        for (int e = 0; e < 4; ++e) {
            int cc = cc0 + e, nt = cc >> 4, nn = cc & 15;
            wfrag[((((skq * 2 + nt) * 8 + kt) * 64) + sq * 16 + nn) * 8 + j] = (_Float16)vv[e];
        }
    }
    __syncthreads();

    half8v wreg[16];                      // [nt*8 + kt]
    #pragma unroll
    for (int nt = 0; nt < 2; ++nt)
        #pragma unroll
        for (int kt = 0; kt < 8; ++kt)
            wreg[nt * 8 + kt] = *(const half8v*)
                &wfrag[((((kq * 2 + nt) * 8 + kt) * 64) + lane) * 8];
    __syncthreads();                      // wfrag dead; gates alias it

    const int pb = tid >> 3, pd = tid & 7;
    const float* bias = cell ? b1 : b0;
    const int gdim = wb * 8 + pd;
    const float bi = bias[0 * 1024 + gdim], bfg = bias[1 * 1024 + gdim],
                bg = bias[2 * 1024 + gdim], bo  = bias[3 * 1024 + gdim];
    float creg = 0.0f;

    const bool havex = (cell == 0) && (kq < 4);   // x-wave: fp32 direct loads

    for (int p = 0; p <= TSTEPS; ++p) {
        if (cell == 0 && p == TSTEPS) break;
        const bool active = cell ? (p >= 1) : true;

        half8v A[4][8];
        // x burst BEFORE the poll (read-only input, overlaps the wait)
        if (havex) {
            const float* xb = x + ((size_t)n15 * 256 + p) * 1024 + kq * 256 + q * 8;
            #pragma unroll
            for (int mt = 0; mt < 4; ++mt) {
                const float* a = xb + (size_t)mt * 16 * 262144;  // +16 batch rows
                #pragma unroll
                for (int kt = 0; kt < 8; ++kt) {
                    float4 u = *(const float4*)(a + kt * 32);
                    float4 v = *(const float4*)(a + kt * 32 + 4);
                    A[mt][kt] = half8v{(_Float16)u.x, (_Float16)u.y, (_Float16)u.z, (_Float16)u.w,
                                       (_Float16)v.x, (_Float16)v.y, (_Float16)v.z, (_Float16)v.w};
                }
            }
        }

        // ---- wait for dependencies: wave 0, leaf-parallel + ballot ----
        if (p >= 1) {
            if (tid < 64) {
                // lanes 0..15: leaf0[p-1]; lanes 16..31 (cell1, p>=2): leaf1[p-1]
                const unsigned* addr = nullptr;
                if (tid < 16) {
                    addr = leaf0 + ((p - 1) * 16 + tid) * 16;
                } else if (tid < 32 && cell == 1 && p >= 2) {
                    addr = leaf1 + ((p - 1) * 16 + (tid - 16)) * 16;
                }
                bool ok = (addr == nullptr);
                while (true) {
                    if (!ok)
                        ok = __hip_atomic_load(addr, __ATOMIC_RELAXED,
                                               __HIP_MEMORY_SCOPE_AGENT) >= 8u;
                    if (__ballot(ok) == ~0ull) break;
                    __builtin_amdgcn_s_sleep(16);
                }
            }
            __syncthreads();
            asm volatile("" ::: "memory");   // no load hoisting above the poll
        }

        // ---- h burst: plain CACHED loads (write-once addresses, L2-amplified)
        if (active && !havex) {
            const _Float16* arow = nullptr;
            if (cell == 0) {
                if (p >= 1) arow = h0s + (size_t)(p - 1) * 65536 + (kq - 4) * 256;
            } else {
                if (kq < 4) arow = h0s + (size_t)(p - 1) * 65536 + kq * 256;
                else if (p >= 2) arow = h1s + (size_t)(p - 2) * 65536 + (kq - 4) * 256;
            }
            if (arow) {
                const _Float16* a = arow + (size_t)n15 * 1024 + q * 8;
                #pragma unroll
                for (int mt = 0; mt < 4; ++mt)
                    #pragma unroll
                    for (int kt = 0; kt < 8; ++kt)
                        A[mt][kt] = *(const half8v*)(a + mt * 16384 + kt * 32);
            } else {
                #pragma unroll
                for (int mt = 0; mt < 4; ++mt)
                    #pragma unroll
                    for (int kt = 0; kt < 8; ++kt)
                        A[mt][kt] = half8v{};          // h[-1] = 0
            }
        }

        // ---- MFMA ----
        if (active) {
            #pragma unroll
            for (int mt = 0; mt < 4; ++mt) {
                f32x4 acc0 = {0.f, 0.f, 0.f, 0.f};
                f32x4 acc1 = {0.f, 0.f, 0.f, 0.f};
                #pragma unroll
                for (int kt = 0; kt < 8; ++kt) {
                    acc0 = __builtin_amdgcn_mfma_f32_16x16x32_f16(A[mt][kt], wreg[kt],     acc0, 0, 0, 0);
                    acc1 = __builtin_amdgcn_mfma_f32_16x16x32_f16(A[mt][kt], wreg[8 + kt], acc1, 0, 0, 0);
                }
                const int row0 = mt * 16 + q * 4;
                #pragma unroll
                for (int r = 0; r < 4; ++r) {
                    gates[(kq * 64 + row0 + r) * GST + n15]      = acc0[r];
                    gates[(kq * 64 + row0 + r) * GST + 16 + n15] = acc1[r];
                }
            }
        }
        __syncthreads();

        // ---- pointwise ----
        if (active) {
            float g0 = 0.f, g1 = 0.f, g2 = 0.f, g3 = 0.f;
            #pragma unroll
            for (int k8 = 0; k8 < 8; ++k8) {
                const float* gsr = gates + (k8 * 64 + pb) * GST + pd;
                g0 += gsr[0]; g1 += gsr[8]; g2 += gsr[16]; g3 += gsr[24];
            }
            g0 += bi; g1 += bfg; g2 += bg; g3 += bo;
            float si = 1.f / (1.f + __expf(-g0));
            float sf = 1.f / (1.f + __expf(-g1));
            float so = 1.f / (1.f + __expf(-g3));
            float cn = sf * creg + si * tanhf(g2);
            float hn = so * tanhf(cn);
            creg = cn;
            union { _Float16 h; unsigned short u; } cv; cv.h = (_Float16)hn;
            _Float16* dst = cell ? (h1s + (size_t)(p - 1) * 65536)
                                 : (h0s + (size_t)p * 65536);
            __hip_atomic_store((unsigned short*)(dst + pb * 1024 + gdim),
                               cv.u, __ATOMIC_RELAXED, __HIP_MEMORY_SCOPE_AGENT);
            if (cell && p == TSTEPS) out[pb * 1024 + gdim] = hn;
        }

        // ---- signal: one leaf add per block (8 blocks/leaf, 64B apart) ----
        if (p < TSTEPS) {
            asm volatile("s_waitcnt vmcnt(0)" ::: "memory");   // h stores at L3
            __syncthreads();
            if (tid == 0)
                __hip_atomic_fetch_add(leafm + (p * 16 + (wb >> 3)) * 16, 1u,
                                       __ATOMIC_RELAXED, __HIP_MEMORY_SCOPE_AGENT);
        }
    }
}

extern "C" void kernel_launch(void* const* d_in, const int* in_sizes, int n_in,
                              void* d_out, int out_size, void* d_ws, size_t ws_size,
                              hipStream_t stream)
{
    const float* x   = (const float*)d_in[0];
    const float* Wx0 = (const float*)d_in[1];
    const float* Wh0 = (const float*)d_in[2];
    const float* b0  = (const float*)d_in[3];
    const float* Wx1 = (const float*)d_in[4];
    const float* Wh1 = (const float*)d_in[5];
    const float* b1  = (const float*)d_in[6];
    float* out = (float*)d_out;

    _Float16* h0s  = (_Float16*)d_ws;                  // 33.55 MB
    _Float16* h1s  = h0s + (size_t)16777216;           // 33.55 MB
    unsigned* cnts = (unsigned*)(h1s + 16777216);      // 512 KB

    hipLaunchKernelGGL(prologue, dim3(512), dim3(256), 0, stream, cnts);

    size_t smem = 131072;
    (void)hipFuncSetAttribute((const void*)lstm_persistent,
                              hipFuncAttributeMaxDynamicSharedMemorySize, (int)smem);

    void* args[] = {(void*)&x, (void*)&Wx0, (void*)&Wh0, (void*)&b0,
                    (void*)&Wx1, (void*)&Wh1, (void*)&b1,
                    (void*)&h0s, (void*)&h1s, (void*)&cnts, (void*)&out};
    (void)hipLaunchCooperativeKernel((const void*)lstm_persistent, dim3(256), dim3(512),
                                     args, (unsigned)smem, stream);
}